// Round 8
// baseline (486.867 us; speedup 1.0000x reference)
//
#include <hip/hip_runtime.h>
#include <cstdint>
#include <cstddef>

#define N_NODES 4096
#define FEAT 128
#define KCH 4
#define NNZ_CAP (1 << 18)   // 262144 entries; expected nnz ~65.5K
#define TB 512              // threads for per-row T-kernels
#define T2CAP 2048          // sparse T2 row stride (expected ~273 nnz/row)

// OpenBLAS sgemm K-panel boundaries for K=4096, GEMM_Q=384 (level3.c balancing):
// 0,384,768,1152,1536,1920,2304,2688,3072,3456,3776,4096
__device__ __forceinline__ int panel_of(int p) {
    return p < 3456 ? (p / 384) : (p < 3776 ? 9 : 10);
}

// ---- Pass 1 (fused): in-degree column counts (int atomics) + out-degree row counts
__global__ __launch_bounds__(256) void k_pass1(const float* __restrict__ adj,
                                               int* __restrict__ deg,
                                               int* __restrict__ rdeg) {
    int wid = (blockIdx.x * 256 + threadIdx.x) >> 6;   // wave id = row
    int lane = threadIdx.x & 63;
    const float* rowp = adj + (size_t)wid * N_NODES;
    int cnt = 0;
    for (int it = 0; it < 64; ++it) {
        int x = it * 64 + lane;
        if (rowp[x] != 0.0f) { atomicAdd(&deg[x], 1); ++cnt; }
    }
    for (int off = 32; off >= 1; off >>= 1) cnt += __shfl_down(cnt, off);
    if (lane == 0) rdeg[wid] = cnt;
}

// ---- Scans: dinv = correctly-rounded fp32 d^-0.5; colptr/colcur from deg; rowptr2 from rdeg
__global__ __launch_bounds__(1024) void k_scan2(const int* __restrict__ deg,
                                                const int* __restrict__ rdeg,
                                                float* __restrict__ dinv,
                                                int* __restrict__ colptr,
                                                int* __restrict__ colcur,
                                                int* __restrict__ rowptr2) {
    __shared__ int part[1024];
    int t = threadIdx.x;
    int v[4]; int s = 0;
    for (int c = 0; c < 4; ++c) {
        int idx = t * 4 + c;
        int di = deg[idx];
        v[c] = di;
        s += di;
        float dc = fmaxf((float)di, 1.0f);
        dinv[idx] = (float)(1.0 / sqrt((double)dc));  // correctly-rounded fp32 x^-0.5
    }
    part[t] = s;
    __syncthreads();
    for (int off = 1; off < 1024; off <<= 1) {
        int add = (t >= off) ? part[t - off] : 0;
        __syncthreads();
        part[t] += add;
        __syncthreads();
    }
    int base = (t == 0) ? 0 : part[t - 1];
    for (int c = 0; c < 4; ++c) {
        int idx = t * 4 + c;
        colptr[idx] = base; colcur[idx] = base;
        base += v[c];
    }
    if (t == 1023) colptr[N_NODES] = base;
    __syncthreads();
    int w4[4]; int s2 = 0;
    for (int c = 0; c < 4; ++c) { w4[c] = rdeg[t * 4 + c]; s2 += w4[c]; }
    part[t] = s2;
    __syncthreads();
    for (int off = 1; off < 1024; off <<= 1) {
        int add = (t >= off) ? part[t - off] : 0;
        __syncthreads();
        part[t] += add;
        __syncthreads();
    }
    int b2 = (t == 0) ? 0 : part[t - 1];
    for (int c = 0; c < 4; ++c) {
        int idx = t * 4 + c;
        rowptr2[idx] = b2;
        b2 += w4[c];
    }
    if (t == 1023) rowptr2[N_NODES] = b2;
}

// ---- Pass 2 (fused): row-CSR (ascending cols, ballot) + col-CSR (atomic cursors)
//      + adjacency BITMASK (bmask[row*64+it] = ballot of columns it*64..it*64+63).
//      dv = fl(dinv_i*dinv_x); rlval = -dv (L entry), val = dv (D entry).
__global__ __launch_bounds__(256) void k_pass2(const float* __restrict__ adj,
                                               const float* __restrict__ dinv,
                                               const int* __restrict__ rowptr2,
                                               int* __restrict__ colcur,
                                               int* __restrict__ rcol,
                                               float* __restrict__ rlval,
                                               int* __restrict__ col_i,
                                               float* __restrict__ val,
                                               unsigned long long* __restrict__ bmask) {
    int row = (blockIdx.x * 256 + threadIdx.x) >> 6;
    int lane = threadIdx.x & 63;
    int rp = rowptr2[row];
    int base = 0;
    float di = dinv[row];
    const float* rowp = adj + (size_t)row * N_NODES;
    for (int it = 0; it < 64; ++it) {
        int x = it * 64 + lane;
        bool nz = rowp[x] != 0.0f;
        unsigned long long m = __ballot(nz);
        if (lane == 0) bmask[(size_t)row * 64 + it] = m;
        if (nz) {
            float dv = di * dinv[x];
            int rank = __popcll(m & ((1ull << lane) - 1ull));
            int e = rp + base + rank;
            if (e < NNZ_CAP) { rcol[e] = x; rlval[e] = -dv; }
            int ec = atomicAdd(&colcur[x], 1);
            if (ec < NNZ_CAP) { col_i[ec] = row; val[ec] = dv; }
        }
        base += __popcll(m);
    }
}

// ---- sW[k][j] = fp32 sequential sum over y (numpy strided-axis reduce order)
__global__ void k_sw(const float* __restrict__ W, float* __restrict__ sW) {
    int tid = blockIdx.x * blockDim.x + threadIdx.x;  // 0..511
    int k = tid >> 7, j = tid & 127;
    float s = 0.f;
    for (int y = 0; y < FEAT; ++y)
        s += fabsf(W[(size_t)j * (KCH * FEAT) + k * FEAT + y]);
    sW[k * FEAT + j] = s;
}

// ---- numpy pairwise_sum over 4096 contiguous fp32 (bitwise replication):
//      32 leaves of 128; leaf = 8 stride-8 accumulator chains, combined
//      ((r0+r1)+(r2+r3))+((r4+r5)+(r6+r7)); leaves combined adjacent-pair binary tree.
__device__ __forceinline__ float np_pairwise_4096(const float* __restrict__ row,
                                                  float* r256, float* leaf,
                                                  float* bc, int t) {
    if (t < 256) {
        int L = t >> 3, j = t & 7;
        const float* p = row + L * 128 + j;
        float a = p[0];
        #pragma unroll
        for (int q = 1; q < 16; ++q) a += p[8 * q];
        r256[t] = a;
    }
    __syncthreads();
    if (t < 32) {
        const float* rr = r256 + t * 8;
        leaf[t] = ((rr[0] + rr[1]) + (rr[2] + rr[3])) + ((rr[4] + rr[5]) + (rr[6] + rr[7]));
    }
    __syncthreads();
    if (t == 0) {
        float v[32];
        #pragma unroll
        for (int q = 0; q < 32; ++q) v[q] = leaf[q];
        #pragma unroll
        for (int w = 16; w >= 1; w >>= 1)
            #pragma unroll
            for (int q = 0; q < 16; ++q)
                if (q < w) v[q] = v[2 * q] + v[2 * q + 1];
        bc[0] = v[0];
    }
    __syncthreads();
    float res = bc[0];
    __syncthreads();
    return res;
}

// ---- Per-row i: s1 = pairwise(L-row); G = (L@L)_row by REGISTER GATHER over the adjacency
//      bitmask (thread t owns x = t+512u): per q ascending, Lval = (x==p)?1 : bit(p,x)?
//      fl(-dinv_p*dinv_x) : 0; pac[u]=fmaf(lv,Lval,pac[u]); panel boundary tot+=pac (regs).
//      Bit-identical to the scatter version: each x gets <=1 term per q; zero terms are
//      fmaf no-ops; fl((-a)b) = -fl(ab). No barriers, no LDS in the main loop.
//      T2 = fl(2G - I); s2 = pairwise; sparse emission.
__global__ __launch_bounds__(TB) void k_t2(const int* __restrict__ rowptr2,
                                           const int* __restrict__ rcol,
                                           const float* __restrict__ rlval,
                                           const float* __restrict__ dinv,
                                           const unsigned long long* __restrict__ bmask,
                                           int2* __restrict__ t2sp,
                                           int* __restrict__ t2cnt,
                                           float* __restrict__ sA) {
    __shared__ float g[N_NODES];
    __shared__ int   pcol[64];
    __shared__ float pLip[64];
    __shared__ float pdinv[64];
    __shared__ int   ssplit;
    __shared__ float r256[256], leaf[32], bc[1];
    __shared__ int   wtot[8], wbase[8];
    int t = threadIdx.x;
    int i = blockIdx.x;
    int rp = rowptr2[i];
    int ol = rowptr2[i + 1] - rp;     // out-degree
    int cnt = ol + 1;                 // + diagonal
    if (cnt > 64) cnt = 64;
    if (t == 0) ssplit = 0;
    __syncthreads();
    if (t < ol && rcol[rp + t] < i) atomicAdd(&ssplit, 1);
    __syncthreads();
    int split = ssplit;
    if (t < cnt) {
        int col; float lip;
        if (t < split)       { col = rcol[rp + t];     lip = rlval[rp + t]; }
        else if (t == split) { col = i;                lip = 1.0f; }
        else                 { col = rcol[rp + t - 1]; lip = rlval[rp + t - 1]; }
        pcol[t] = col; pLip[t] = lip; pdinv[t] = dinv[col];
    }
    // per-thread dinv[x] registers
    float dinvx[8];
    #pragma unroll
    for (int u = 0; u < 8; ++u) dinvx[u] = dinv[t + u * TB];
    // ---- s1: dense L-row(i) (off-diag rlval + diag 1.0), numpy pairwise
    #pragma unroll
    for (int u = 0; u < 8; ++u) g[t + u * TB] = 0.0f;
    __syncthreads();
    for (int e = t; e < ol; e += TB) g[rcol[rp + e]] = rlval[rp + e];
    if (t == 0) g[i] = 1.0f;
    __syncthreads();
    float s1 = np_pairwise_4096(g, r256, leaf, bc, t);
    // ---- G = (L@L) row i: register gather with sgemm K-panel folds
    float tot[8], pac[8];
    #pragma unroll
    for (int u = 0; u < 8; ++u) { tot[u] = 0.0f; pac[u] = 0.0f; }
    int q = 0;
    while (q < cnt) {
        int pid = panel_of(pcol[q]);
        while (q < cnt && panel_of(pcol[q]) == pid) {
            int p = pcol[q];
            float lv = pLip[q];
            float ndp = -pdinv[q];
            const unsigned long long* mrow = bmask + (size_t)p * 64;
            #pragma unroll
            for (int u = 0; u < 8; ++u) {
                int x = t + u * TB;
                unsigned long long mw = mrow[x >> 6];
                bool bit = (mw >> (x & 63)) & 1ull;
                float lval = bit ? (ndp * dinvx[u]) : 0.0f;
                if (x == p) lval = 1.0f;               // adj diag is 0 -> no double count
                pac[u] = fmaf(lv, lval, pac[u]);
            }
            ++q;
        }
        #pragma unroll
        for (int u = 0; u < 8; ++u) { tot[u] = tot[u] + pac[u]; pac[u] = 0.0f; }
    }
    // T2 entries fl(2G - I), dense write (coalesced, conflict-free)
    #pragma unroll
    for (int u = 0; u < 8; ++u) {
        int x = t + u * TB;
        g[x] = 2.0f * tot[u] - (x == i ? 1.0f : 0.0f);
    }
    __syncthreads();
    float s2 = np_pairwise_4096(g, r256, leaf, bc, t);
    // ---- sparse emission (ascending col): thread t owns x in [8t, 8t+8)
    int cl = 0;
    #pragma unroll
    for (int u = 0; u < 8; ++u) cl += (g[t * 8 + u] != 0.0f);
    int lane = t & 63, wv = t >> 6;
    int sc = cl;
    for (int off = 1; off < 64; off <<= 1) {
        int n = __shfl_up(sc, off);
        if (lane >= off) sc += n;
    }
    if (lane == 63) wtot[wv] = sc;
    __syncthreads();
    if (t == 0) {
        int b = 0;
        for (int wq = 0; wq < 8; ++wq) { wbase[wq] = b; b += wtot[wq]; }
        t2cnt[i] = (b > T2CAP) ? T2CAP : b;
    }
    __syncthreads();
    int pos = wbase[wv] + sc - cl;
    int2* dst = t2sp + (size_t)i * T2CAP;
    #pragma unroll
    for (int u = 0; u < 8; ++u) {
        float v = g[t * 8 + u];
        if (v != 0.0f) {
            if (pos < T2CAP) dst[pos] = make_int2(t * 8 + u, __float_as_int(v));
            ++pos;
        }
    }
    if (t == 0) {
        sA[0 * N_NODES + i] = 1.0f;
        sA[1 * N_NODES + i] = s1;
        sA[2 * N_NODES + i] = s2;
    }
}

// ---- Per-row i: H = (L@T2)_row via sparse T2 rows (R5-proven register-fold version):
//      within-panel fmaf scatter into LDS partial (barrier per q preserves q-order),
//      per-panel fold into register totals (one rounding). T3 = fl(2H - T1); s3 = pairwise.
__global__ __launch_bounds__(TB) void k_t3(const int* __restrict__ rowptr2,
                                           const int* __restrict__ rcol,
                                           const float* __restrict__ rlval,
                                           const int2* __restrict__ t2sp,
                                           const int* __restrict__ t2cnt,
                                           float* __restrict__ sA) {
    __shared__ float gp[N_NODES];     // panel partial, then final T3 row
    __shared__ int   pcol[64];
    __shared__ float pLip[64];
    __shared__ int   ssplit;
    __shared__ float r256[256], leaf[32], bc[1];
    int t = threadIdx.x;
    int i = blockIdx.x;
    int rp = rowptr2[i];
    int ol = rowptr2[i + 1] - rp;
    int cnt = ol + 1;
    if (cnt > 64) cnt = 64;
    if (t == 0) ssplit = 0;
    __syncthreads();
    if (t < ol && rcol[rp + t] < i) atomicAdd(&ssplit, 1);
    __syncthreads();
    int split = ssplit;
    if (t < cnt) {
        if (t < split)       { pcol[t] = rcol[rp + t];     pLip[t] = rlval[rp + t]; }
        else if (t == split) { pcol[t] = i;                pLip[t] = 1.0f; }
        else                 { pcol[t] = rcol[rp + t - 1]; pLip[t] = rlval[rp + t - 1]; }
    }
    #pragma unroll
    for (int u = 0; u < 8; ++u) gp[t + u * TB] = 0.0f;
    __syncthreads();
    float tot[8];
    #pragma unroll
    for (int u = 0; u < 8; ++u) tot[u] = 0.0f;
    int q = 0;
    while (q < cnt) {
        int pid = panel_of(pcol[q]);
        while (q < cnt && panel_of(pcol[q]) == pid) {
            float lv = pLip[q];
            int p = pcol[q];
            int nn = t2cnt[p];
            const int2* sp = t2sp + (size_t)p * T2CAP;
            for (int e = t; e < nn; e += TB) {
                int2 en = sp[e];
                gp[en.x] = fmaf(lv, __int_as_float(en.y), gp[en.x]);
            }
            __syncthreads();
            ++q;
        }
        // panel-boundary rounding: fold partial into totals, reset partial
        #pragma unroll
        for (int u = 0; u < 8; ++u) {
            int x = t + u * TB;
            tot[u] = tot[u] + gp[x];
            gp[x] = 0.0f;
        }
        __syncthreads();
    }
    #pragma unroll
    for (int u = 0; u < 8; ++u) gp[t + u * TB] = 2.0f * tot[u];  // exact x2
    __syncthreads();
    for (int e = t; e < ol; e += TB) { int x = rcol[rp + e]; gp[x] = gp[x] - rlval[rp + e]; }
    if (t == 0) gp[i] = gp[i] - 1.0f;
    __syncthreads();
    float s3 = np_pairwise_4096(gp, r256, leaf, bc, t);
    if (t == 0) sA[3 * N_NODES + i] = s3;
}

// ---- c[i,j] = r[i,j]/denom; denom = ascending-k, separate mul+add roundings (numpy einsum sop)
__global__ void k_c(const float* __restrict__ r, const float* __restrict__ sA,
                    const float* __restrict__ sW, float* __restrict__ c) {
#pragma clang fp contract(off)
    int gid = blockIdx.x * blockDim.x + threadIdx.x;
    int i = gid >> 7, j = gid & 127;
    float denom = 0.0f;
    #pragma unroll
    for (int k = 0; k < KCH; ++k) {
        float p = sA[k * N_NODES + i] * sW[k * FEAT + j];
        denom = denom + p;
    }
    c[gid] = r[gid] / denom;
}

// ---- M_k[i,y] = sum_j c[i,j] * |W[j, k*128+y]|
__global__ __launch_bounds__(256) void k_m(const float* __restrict__ c,
                                           const float* __restrict__ W,
                                           float* __restrict__ M) {
    __shared__ float cl[32][FEAT];
    int k = blockIdx.y;
    int ib = blockIdx.x * 32;
    int tx = threadIdx.x;
    int y = tx & 127, half = tx >> 7;
    for (int m = tx; m < 32 * FEAT; m += 256)
        cl[m >> 7][m & 127] = c[(size_t)(ib + (m >> 7)) * FEAT + (m & 127)];
    __syncthreads();
    float acc[16];
    #pragma unroll
    for (int u = 0; u < 16; ++u) acc[u] = 0.0f;
    for (int j = 0; j < FEAT; ++j) {
        float a = fabsf(W[(size_t)j * (KCH * FEAT) + k * FEAT + y]);
        #pragma unroll
        for (int u = 0; u < 16; ++u) acc[u] += a * cl[half * 16 + u][j];
    }
    #pragma unroll
    for (int u = 0; u < 16; ++u)
        M[(size_t)k * N_NODES * FEAT + (size_t)(ib + half * 16 + u) * FEAT + y] = acc[u];
}

// ---- fused double Laplacian gather: out1 = A1 - D^T A1 ; out2 = A2 - D^T A2
__global__ void k_lap2(const int* __restrict__ colptr, const int* __restrict__ col_i,
                       const float* __restrict__ val,
                       const float* __restrict__ A1, const float* __restrict__ A2,
                       float* __restrict__ out1, float* __restrict__ out2) {
    int x = blockIdx.x * 2 + (threadIdx.x >> 7);
    int y = threadIdx.x & 127;
    int e0 = colptr[x], e1 = colptr[x + 1];
    if (e1 > NNZ_CAP) e1 = NNZ_CAP;
    float a1 = 0.0f, a2 = 0.0f;
    for (int e = e0; e < e1; ++e) {
        int i = col_i[e];
        float v = val[e];
        size_t o = (size_t)i * FEAT + y;
        a1 += v * A1[o];
        a2 += v * A2[o];
    }
    size_t o = (size_t)x * FEAT + y;
    out1[o] = A1[o] - a1;
    out2[o] = A2[o] - a2;
}

// ---- out = A - D^T A  (one sparse gather per output row x)
__global__ void k_lap(const int* __restrict__ colptr, const int* __restrict__ col_i,
                      const float* __restrict__ val, const float* __restrict__ A,
                      float* __restrict__ out) {
    int x = blockIdx.x * 2 + (threadIdx.x >> 7);
    int y = threadIdx.x & 127;
    int e0 = colptr[x], e1 = colptr[x + 1];
    if (e1 > NNZ_CAP) e1 = NNZ_CAP;
    float acc = 0.0f;
    for (int e = e0; e < e1; ++e)
        acc += val[e] * A[(size_t)col_i[e] * FEAT + y];
    out[(size_t)x * FEAT + y] = A[(size_t)x * FEAT + y] - acc;
}

// ---- out = M0 + (M1 - D'M1) + (2(U - D'U) - M2) + (4(S - D'S) - 3R)
__global__ void k_final(const int* __restrict__ colptr, const int* __restrict__ col_i,
                        const float* __restrict__ val, const float* __restrict__ M,
                        const float* __restrict__ U, const float* __restrict__ R,
                        const float* __restrict__ S, float* __restrict__ out) {
    int x = blockIdx.x * 2 + (threadIdx.x >> 7);
    int y = threadIdx.x & 127;
    const float* M0 = M;
    const float* M1 = M + (size_t)N_NODES * FEAT;
    const float* M2 = M + (size_t)2 * N_NODES * FEAT;
    int e0 = colptr[x], e1 = colptr[x + 1];
    if (e1 > NNZ_CAP) e1 = NNZ_CAP;
    float g1 = 0.f, g2 = 0.f, g3 = 0.f;
    for (int e = e0; e < e1; ++e) {
        int i = col_i[e];
        float v = val[e];
        size_t o = (size_t)i * FEAT + y;
        g1 += v * M1[o];
        g2 += v * U[o];
        g3 += v * S[o];
    }
    size_t o = (size_t)x * FEAT + y;
    out[o] = M0[o] + (M1[o] - g1) + (2.0f * (U[o] - g2) - M2[o])
           + (4.0f * (S[o] - g3) - 3.0f * R[o]);
}

extern "C" void kernel_launch(void* const* d_in, const int* in_sizes, int n_in,
                              void* d_out, int out_size, void* d_ws, size_t ws_size,
                              hipStream_t stream) {
    const float* r   = (const float*)d_in[1];
    const float* adj = (const float*)d_in[2];
    const float* W   = (const float*)d_in[3];
    float* out = (float*)d_out;

    char* w = (char*)d_ws;
    auto take = [&](size_t bytes) {
        char* p = w;
        w += (bytes + 255) & ~(size_t)255;
        return p;
    };
    int*   deg     = (int*)take((size_t)N_NODES * 4);
    int*   rdeg    = (int*)take((size_t)N_NODES * 4);
    float* dinv    = (float*)take((size_t)N_NODES * 4);
    int*   colcur  = (int*)take((size_t)N_NODES * 4);
    int*   colptr  = (int*)take((size_t)(N_NODES + 1) * 4);
    int*   rowptr2 = (int*)take((size_t)(N_NODES + 1) * 4);
    int*   col_i   = (int*)take((size_t)NNZ_CAP * 4);
    float* val     = (float*)take((size_t)NNZ_CAP * 4);
    int*   rcol    = (int*)take((size_t)NNZ_CAP * 4);
    float* rlval   = (float*)take((size_t)NNZ_CAP * 4);
    float* sW      = (float*)take((size_t)KCH * FEAT * 4);
    float* sA      = (float*)take((size_t)KCH * N_NODES * 4);
    float* c       = (float*)take((size_t)N_NODES * FEAT * 4);
    float* M       = (float*)take((size_t)KCH * N_NODES * FEAT * 4);
    float* U       = (float*)take((size_t)N_NODES * FEAT * 4);
    float* R       = (float*)take((size_t)N_NODES * FEAT * 4);
    float* S       = (float*)take((size_t)N_NODES * FEAT * 4);
    int*   t2cnt   = (int*)take((size_t)N_NODES * 4);
    int2*  t2sp    = (int2*)take((size_t)N_NODES * T2CAP * 8);   // 64 MB sparse T2
    unsigned long long* bmask = (unsigned long long*)take((size_t)N_NODES * 64 * 8); // 2 MB

    hipMemsetAsync(deg, 0, (size_t)N_NODES * 4, stream);
    k_pass1<<<N_NODES / 4, 256, 0, stream>>>(adj, deg, rdeg);
    k_scan2<<<1, 1024, 0, stream>>>(deg, rdeg, dinv, colptr, colcur, rowptr2);
    k_pass2<<<N_NODES / 4, 256, 0, stream>>>(adj, dinv, rowptr2, colcur,
                                             rcol, rlval, col_i, val, bmask);
    k_sw<<<2, 256, 0, stream>>>(W, sW);
    k_t2<<<N_NODES, TB, 0, stream>>>(rowptr2, rcol, rlval, dinv, bmask, t2sp, t2cnt, sA);
    k_t3<<<N_NODES, TB, 0, stream>>>(rowptr2, rcol, rlval, t2sp, t2cnt, sA);
    k_c<<<(N_NODES * FEAT) / 256, 256, 0, stream>>>(r, sA, sW, c);
    k_m<<<dim3(N_NODES / 32, KCH), 256, 0, stream>>>(c, W, M);
    // U = L^T M2 ; R = L^T M3 (fused) ; S = L^T R
    k_lap2<<<N_NODES / 2, 256, 0, stream>>>(colptr, col_i, val,
                                            M + (size_t)2 * N_NODES * FEAT,
                                            M + (size_t)3 * N_NODES * FEAT, U, R);
    k_lap<<<N_NODES / 2, 256, 0, stream>>>(colptr, col_i, val, R, S);
    k_final<<<N_NODES / 2, 256, 0, stream>>>(colptr, col_i, val, M, U, R, S, out);
}

// Round 9
// 419.942 us; speedup vs baseline: 1.1594x; 1.1594x over previous
//
#include <hip/hip_runtime.h>
#include <cstdint>
#include <cstddef>

#define N_NODES 4096
#define FEAT 128
#define KCH 4
#define NNZ_CAP (1 << 18)   // col-CSR cap; expected nnz ~65.5K
#define TB 512              // threads for per-row T-kernels
#define T2CAP 2048          // sparse T2 row stride (expected ~273 nnz/row)
#define RSTRIDE 96          // fixed row-list stride (max out-degree ~40 expected)

// OpenBLAS sgemm K-panel boundaries for K=4096, GEMM_Q=384 (level3.c balancing):
// 0,384,768,1152,1536,1920,2304,2688,3072,3456,3776,4096
__device__ __forceinline__ int panel_of(int p) {
    return p < 3456 ? (p / 384) : (p < 3776 ? 9 : 10);
}

// ---- Single adjacency pass: per-row ascending column lists (fixed stride) + out-degree
//      + in-degree column counts (int atomics). One 64 MB read total.
__global__ __launch_bounds__(256) void k_adj(const float* __restrict__ adj,
                                             int* __restrict__ deg,
                                             int* __restrict__ rdeg,
                                             int* __restrict__ rcolF) {
    int row = (blockIdx.x * 256 + threadIdx.x) >> 6;   // wave per row
    int lane = threadIdx.x & 63;
    const float* rowp = adj + (size_t)row * N_NODES;
    int base = 0;
    for (int it = 0; it < 64; ++it) {
        int x = it * 64 + lane;
        bool nz = rowp[x] != 0.0f;
        unsigned long long m = __ballot(nz);
        if (nz) {
            int idx = base + __popcll(m & ((1ull << lane) - 1ull));
            if (idx < RSTRIDE) rcolF[row * RSTRIDE + idx] = x;
            atomicAdd(&deg[x], 1);
        }
        base += __popcll(m);
    }
    if (lane == 0) rdeg[row] = (base > RSTRIDE) ? RSTRIDE : base;
}

// ---- Scan: dinv = correctly-rounded fp32 d^-0.5; colptr/colcur from deg
__global__ __launch_bounds__(1024) void k_scan(const int* __restrict__ deg,
                                               float* __restrict__ dinv,
                                               int* __restrict__ colptr,
                                               int* __restrict__ colcur) {
    __shared__ int part[1024];
    int t = threadIdx.x;
    int v[4]; int s = 0;
    for (int c = 0; c < 4; ++c) {
        int idx = t * 4 + c;
        int di = deg[idx];
        v[c] = di;
        s += di;
        float dc = fmaxf((float)di, 1.0f);
        dinv[idx] = (float)(1.0 / sqrt((double)dc));  // correctly-rounded fp32 x^-0.5
    }
    part[t] = s;
    __syncthreads();
    for (int off = 1; off < 1024; off <<= 1) {
        int add = (t >= off) ? part[t - off] : 0;
        __syncthreads();
        part[t] += add;
        __syncthreads();
    }
    int base = (t == 0) ? 0 : part[t - 1];
    for (int c = 0; c < 4; ++c) {
        int idx = t * 4 + c;
        colptr[idx] = base; colcur[idx] = base;
        base += v[c];
    }
    if (t == 1023) colptr[N_NODES] = base;
}

// ---- Values pass (tiny): rlvalF = -fl(dinv_i*dinv_x); col-CSR (col_i, val) via cursors
__global__ __launch_bounds__(256) void k_vals(const float* __restrict__ dinv,
                                              const int* __restrict__ rdeg,
                                              const int* __restrict__ rcolF,
                                              float* __restrict__ rlvalF,
                                              int* __restrict__ colcur,
                                              int* __restrict__ col_i,
                                              float* __restrict__ val) {
    int row = (blockIdx.x * 256 + threadIdx.x) >> 6;
    int lane = threadIdx.x & 63;
    int n = rdeg[row];
    float di = dinv[row];
    for (int e = lane; e < n; e += 64) {
        int x = rcolF[row * RSTRIDE + e];
        float dv = di * dinv[x];
        rlvalF[row * RSTRIDE + e] = -dv;
        int ec = atomicAdd(&colcur[x], 1);
        if (ec < NNZ_CAP) { col_i[ec] = row; val[ec] = dv; }
    }
}

// ---- sW[k][j] = fp32 sequential sum over y (numpy strided-axis reduce order)
__global__ void k_sw(const float* __restrict__ W, float* __restrict__ sW) {
    int tid = blockIdx.x * blockDim.x + threadIdx.x;  // 0..511
    int k = tid >> 7, j = tid & 127;
    float s = 0.f;
    for (int y = 0; y < FEAT; ++y)
        s += fabsf(W[(size_t)j * (KCH * FEAT) + k * FEAT + y]);
    sW[k * FEAT + j] = s;
}

// ---- numpy pairwise_sum over 4096 contiguous fp32 (bitwise replication)
__device__ __forceinline__ float np_pairwise_4096(const float* __restrict__ row,
                                                  float* r256, float* leaf,
                                                  float* bc, int t) {
    if (t < 256) {
        int L = t >> 3, j = t & 7;
        const float* p = row + L * 128 + j;
        float a = p[0];
        #pragma unroll
        for (int q = 1; q < 16; ++q) a += p[8 * q];
        r256[t] = a;
    }
    __syncthreads();
    if (t < 32) {
        const float* rr = r256 + t * 8;
        leaf[t] = ((rr[0] + rr[1]) + (rr[2] + rr[3])) + ((rr[4] + rr[5]) + (rr[6] + rr[7]));
    }
    __syncthreads();
    if (t == 0) {
        float v[32];
        #pragma unroll
        for (int q = 0; q < 32; ++q) v[q] = leaf[q];
        #pragma unroll
        for (int w = 16; w >= 1; w >>= 1)
            #pragma unroll
            for (int q = 0; q < 16; ++q)
                if (q < w) v[q] = v[2 * q] + v[2 * q + 1];
        bc[0] = v[0];
    }
    __syncthreads();
    float res = bc[0];
    __syncthreads();
    return res;
}

// ---- R5-PROVEN k_t2 (bit-exact), adapted to fixed-stride row lists (same entries, same
//      q-order, same staging, same dense panel folds -> identical rounding sequence).
__global__ __launch_bounds__(TB) void k_t2(const int* __restrict__ rdeg,
                                           const int* __restrict__ rcolF,
                                           const float* __restrict__ rlvalF,
                                           int2* __restrict__ t2sp,
                                           int* __restrict__ t2cnt,
                                           float* __restrict__ sA) {
    __shared__ float g[N_NODES];      // totals / dense row
    __shared__ float gp[N_NODES];     // current-panel partial
    __shared__ int   scol[2048];
    __shared__ float sval[2048];
    __shared__ int   pcol[64];
    __shared__ float pLip[64];
    __shared__ int   pbeg[64], plen[64], poff[65];
    __shared__ int   ssplit;
    __shared__ float r256[256], leaf[32], bc[1];
    __shared__ int   wtot[8], wbase[8];
    int t = threadIdx.x;
    int i = blockIdx.x;
    int rp = i * RSTRIDE;
    int ol = rdeg[i];                 // out-degree
    int cnt = ol + 1;                 // + diagonal
    if (cnt > 64) cnt = 64;
    if (t == 0) ssplit = 0;
    __syncthreads();
    if (t < ol && rcolF[rp + t] < i) atomicAdd(&ssplit, 1);
    __syncthreads();
    int split = ssplit;
    if (t < cnt) {
        int col; float lip;
        if (t < split)       { col = rcolF[rp + t];     lip = rlvalF[rp + t]; }
        else if (t == split) { col = i;                 lip = 1.0f; }
        else                 { col = rcolF[rp + t - 1]; lip = rlvalF[rp + t - 1]; }
        pcol[t] = col; pLip[t] = lip;
        pbeg[t] = col * RSTRIDE;
        plen[t] = rdeg[col] + 1;      // + synthetic diagonal
    }
    __syncthreads();
    if (t == 0) {
        int o = 0;
        for (int q = 0; q < cnt; ++q) { poff[q] = o; o += plen[q]; }
        poff[cnt] = o;
    }
    __syncthreads();
    int E = poff[cnt]; if (E > 2048) E = 2048;
    for (int idx = t; idx < E; idx += TB) {
        int lo = 0, hi = cnt - 1;
        while (lo < hi) { int mid = (lo + hi + 1) >> 1; if (poff[mid] <= idx) lo = mid; else hi = mid - 1; }
        int e = idx - poff[lo];
        if (e == plen[lo] - 1) { scol[idx] = pcol[lo]; sval[idx] = 1.0f; }
        else                   { scol[idx] = rcolF[pbeg[lo] + e]; sval[idx] = rlvalF[pbeg[lo] + e]; }
    }
    // ---- s1: dense L-row(i), numpy pairwise
    for (int x = t; x < N_NODES; x += TB) g[x] = 0.0f;
    __syncthreads();
    {
        int q0 = split;  // own-row segment (entries + synthetic diag) IS the L-row
        for (int e = t; e < plen[q0]; e += TB) { int idx = poff[q0] + e; g[scol[idx]] = sval[idx]; }
    }
    __syncthreads();
    float s1 = np_pairwise_4096(g, r256, leaf, bc, t);
    // ---- G = (L@L) row i with sgemm K-panels: q-ascending fmaf scatter (barrier per q),
    //      dense panel-boundary fold (one rounding per panel)
    for (int x = t; x < N_NODES; x += TB) { g[x] = 0.0f; gp[x] = 0.0f; }
    __syncthreads();
    int q = 0;
    while (q < cnt) {
        int pid = panel_of(pcol[q]);
        while (q < cnt && panel_of(pcol[q]) == pid) {
            float lv = pLip[q];
            int o = poff[q], Lq = plen[q];
            for (int e = t; e < Lq; e += TB) {
                int idx = o + e; int x = scol[idx];
                gp[x] = fmaf(lv, sval[idx], gp[x]);
            }
            __syncthreads();
            ++q;
        }
        for (int x = t; x < N_NODES; x += TB) { g[x] = g[x] + gp[x]; gp[x] = 0.0f; }
        __syncthreads();
    }
    // T2 entries fl(2G - I)
    for (int x = t; x < N_NODES; x += TB) {
        float v = 2.0f * g[x] - (x == i ? 1.0f : 0.0f);
        g[x] = v;
    }
    __syncthreads();
    float s2 = np_pairwise_4096(g, r256, leaf, bc, t);
    // ---- sparse emission (ascending col): thread t owns x in [8t, 8t+8)
    int cl = 0;
    #pragma unroll
    for (int u = 0; u < 8; ++u) cl += (g[t * 8 + u] != 0.0f);
    int lane = t & 63, wv = t >> 6;
    int sc = cl;
    for (int off = 1; off < 64; off <<= 1) {
        int n = __shfl_up(sc, off);
        if (lane >= off) sc += n;
    }
    if (lane == 63) wtot[wv] = sc;
    __syncthreads();
    if (t == 0) {
        int b = 0;
        for (int wq = 0; wq < 8; ++wq) { wbase[wq] = b; b += wtot[wq]; }
        t2cnt[i] = (b > T2CAP) ? T2CAP : b;
    }
    __syncthreads();
    int pos = wbase[wv] + sc - cl;
    int2* dst = t2sp + (size_t)i * T2CAP;
    #pragma unroll
    for (int u = 0; u < 8; ++u) {
        float v = g[t * 8 + u];
        if (v != 0.0f) {
            if (pos < T2CAP) dst[pos] = make_int2(t * 8 + u, __float_as_int(v));
            ++pos;
        }
    }
    if (t == 0) {
        sA[0 * N_NODES + i] = 1.0f;
        sA[1 * N_NODES + i] = s1;
        sA[2 * N_NODES + i] = s2;
    }
}

// ---- R5-PROVEN k_t3 (bit-exact), fixed-stride adapted: sparse T2 scatter per q (barrier),
//      per-panel register fold. T3 = fl(2H - T1); s3 = pairwise. T3 never stored.
__global__ __launch_bounds__(TB) void k_t3(const int* __restrict__ rdeg,
                                           const int* __restrict__ rcolF,
                                           const float* __restrict__ rlvalF,
                                           const int2* __restrict__ t2sp,
                                           const int* __restrict__ t2cnt,
                                           float* __restrict__ sA) {
    __shared__ float gp[N_NODES];     // panel partial, then final T3 row
    __shared__ int   pcol[64];
    __shared__ float pLip[64];
    __shared__ int   ssplit;
    __shared__ float r256[256], leaf[32], bc[1];
    int t = threadIdx.x;
    int i = blockIdx.x;
    int rp = i * RSTRIDE;
    int ol = rdeg[i];
    int cnt = ol + 1;
    if (cnt > 64) cnt = 64;
    if (t == 0) ssplit = 0;
    __syncthreads();
    if (t < ol && rcolF[rp + t] < i) atomicAdd(&ssplit, 1);
    __syncthreads();
    int split = ssplit;
    if (t < cnt) {
        if (t < split)       { pcol[t] = rcolF[rp + t];     pLip[t] = rlvalF[rp + t]; }
        else if (t == split) { pcol[t] = i;                  pLip[t] = 1.0f; }
        else                 { pcol[t] = rcolF[rp + t - 1];  pLip[t] = rlvalF[rp + t - 1]; }
    }
    #pragma unroll
    for (int u = 0; u < 8; ++u) gp[t + u * TB] = 0.0f;
    __syncthreads();
    float tot[8];
    #pragma unroll
    for (int u = 0; u < 8; ++u) tot[u] = 0.0f;
    int q = 0;
    while (q < cnt) {
        int pid = panel_of(pcol[q]);
        while (q < cnt && panel_of(pcol[q]) == pid) {
            float lv = pLip[q];
            int p = pcol[q];
            int nn = t2cnt[p];
            const int2* sp = t2sp + (size_t)p * T2CAP;
            for (int e = t; e < nn; e += TB) {
                int2 en = sp[e];
                gp[en.x] = fmaf(lv, __int_as_float(en.y), gp[en.x]);
            }
            __syncthreads();
            ++q;
        }
        // panel-boundary rounding: fold partial into totals, reset partial
        #pragma unroll
        for (int u = 0; u < 8; ++u) {
            int x = t + u * TB;
            tot[u] = tot[u] + gp[x];
            gp[x] = 0.0f;
        }
        __syncthreads();
    }
    #pragma unroll
    for (int u = 0; u < 8; ++u) gp[t + u * TB] = 2.0f * tot[u];  // exact x2
    __syncthreads();
    for (int e = t; e < ol; e += TB) { int x = rcolF[rp + e]; gp[x] = gp[x] - rlvalF[rp + e]; }
    if (t == 0) gp[i] = gp[i] - 1.0f;
    __syncthreads();
    float s3 = np_pairwise_4096(gp, r256, leaf, bc, t);
    if (t == 0) sA[3 * N_NODES + i] = s3;
}

// ---- Fused c + M: c[i,j] = r[i,j]/denom (exact k_c arithmetic: non-contracted,
//      ascending-k mul then add); M_k[i,y] = sum_j c[i,j]*|W[j,k*128+y]|
__global__ __launch_bounds__(256) void k_cm(const float* __restrict__ r,
                                            const float* __restrict__ sA,
                                            const float* __restrict__ sW,
                                            const float* __restrict__ W,
                                            float* __restrict__ M) {
#pragma clang fp contract(off)
    __shared__ float cl[32][FEAT];
    int k = blockIdx.y;
    int ib = blockIdx.x * 32;
    int tx = threadIdx.x;
    int y = tx & 127, half = tx >> 7;
    for (int m = tx; m < 32 * FEAT; m += 256) {
        int i = ib + (m >> 7), j = m & 127;
        float denom = 0.0f;
        #pragma unroll
        for (int k2 = 0; k2 < KCH; ++k2) {
            float p = sA[k2 * N_NODES + i] * sW[k2 * FEAT + j];
            denom = denom + p;
        }
        cl[m >> 7][m & 127] = r[(size_t)i * FEAT + j] / denom;
    }
    __syncthreads();
    float acc[16];
    #pragma unroll
    for (int u = 0; u < 16; ++u) acc[u] = 0.0f;
    for (int j = 0; j < FEAT; ++j) {
        float a = fabsf(W[(size_t)j * (KCH * FEAT) + k * FEAT + y]);
        #pragma unroll
        for (int u = 0; u < 16; ++u) acc[u] += a * cl[half * 16 + u][j];
    }
    #pragma unroll
    for (int u = 0; u < 16; ++u)
        M[(size_t)k * N_NODES * FEAT + (size_t)(ib + half * 16 + u) * FEAT + y] = acc[u];
}

// ---- Horner output chain: out = M0 - M2 + Lap(M1 - 3M3 + Lap(2M2 + Lap(4M3))),
//      Lap(A) = A - D^T A. Three gather applications total.
// h1: B2 = 2M2 + 4*(M3 - D'M3)
__global__ void k_h1(const int* __restrict__ colptr, const int* __restrict__ col_i,
                     const float* __restrict__ val, const float* __restrict__ M,
                     float* __restrict__ B2) {
    int x = blockIdx.x * 2 + (threadIdx.x >> 7);
    int y = threadIdx.x & 127;
    const float* M2 = M + (size_t)2 * N_NODES * FEAT;
    const float* M3 = M + (size_t)3 * N_NODES * FEAT;
    int e0 = colptr[x], e1 = colptr[x + 1];
    if (e1 > NNZ_CAP) e1 = NNZ_CAP;
    float g = 0.0f;
    for (int e = e0; e < e1; ++e)
        g += val[e] * M3[(size_t)col_i[e] * FEAT + y];
    size_t o = (size_t)x * FEAT + y;
    B2[o] = 2.0f * M2[o] + 4.0f * (M3[o] - g);
}

// h2: B3 = (M1 - 3M3) + (B2 - D'B2)
__global__ void k_h2(const int* __restrict__ colptr, const int* __restrict__ col_i,
                     const float* __restrict__ val, const float* __restrict__ M,
                     const float* __restrict__ B2, float* __restrict__ B3) {
    int x = blockIdx.x * 2 + (threadIdx.x >> 7);
    int y = threadIdx.x & 127;
    const float* M1 = M + (size_t)N_NODES * FEAT;
    const float* M3 = M + (size_t)3 * N_NODES * FEAT;
    int e0 = colptr[x], e1 = colptr[x + 1];
    if (e1 > NNZ_CAP) e1 = NNZ_CAP;
    float g = 0.0f;
    for (int e = e0; e < e1; ++e)
        g += val[e] * B2[(size_t)col_i[e] * FEAT + y];
    size_t o = (size_t)x * FEAT + y;
    B3[o] = (M1[o] - 3.0f * M3[o]) + (B2[o] - g);
}

// h3: out = (M0 - M2) + (B3 - D'B3)
__global__ void k_h3(const int* __restrict__ colptr, const int* __restrict__ col_i,
                     const float* __restrict__ val, const float* __restrict__ M,
                     const float* __restrict__ B3, float* __restrict__ out) {
    int x = blockIdx.x * 2 + (threadIdx.x >> 7);
    int y = threadIdx.x & 127;
    const float* M0 = M;
    const float* M2 = M + (size_t)2 * N_NODES * FEAT;
    int e0 = colptr[x], e1 = colptr[x + 1];
    if (e1 > NNZ_CAP) e1 = NNZ_CAP;
    float g = 0.0f;
    for (int e = e0; e < e1; ++e)
        g += val[e] * B3[(size_t)col_i[e] * FEAT + y];
    size_t o = (size_t)x * FEAT + y;
    out[o] = (M0[o] - M2[o]) + (B3[o] - g);
}

extern "C" void kernel_launch(void* const* d_in, const int* in_sizes, int n_in,
                              void* d_out, int out_size, void* d_ws, size_t ws_size,
                              hipStream_t stream) {
    const float* r   = (const float*)d_in[1];
    const float* adj = (const float*)d_in[2];
    const float* W   = (const float*)d_in[3];
    float* out = (float*)d_out;

    char* w = (char*)d_ws;
    auto take = [&](size_t bytes) {
        char* p = w;
        w += (bytes + 255) & ~(size_t)255;
        return p;
    };
    int*   deg    = (int*)take((size_t)N_NODES * 4);
    int*   rdeg   = (int*)take((size_t)N_NODES * 4);
    float* dinv   = (float*)take((size_t)N_NODES * 4);
    int*   colcur = (int*)take((size_t)N_NODES * 4);
    int*   colptr = (int*)take((size_t)(N_NODES + 1) * 4);
    int*   col_i  = (int*)take((size_t)NNZ_CAP * 4);
    float* val    = (float*)take((size_t)NNZ_CAP * 4);
    int*   rcolF  = (int*)take((size_t)N_NODES * RSTRIDE * 4);
    float* rlvalF = (float*)take((size_t)N_NODES * RSTRIDE * 4);
    float* sW     = (float*)take((size_t)KCH * FEAT * 4);
    float* sA     = (float*)take((size_t)KCH * N_NODES * 4);
    float* M      = (float*)take((size_t)KCH * N_NODES * FEAT * 4);
    float* B2     = (float*)take((size_t)N_NODES * FEAT * 4);
    float* B3     = (float*)take((size_t)N_NODES * FEAT * 4);
    int*   t2cnt  = (int*)take((size_t)N_NODES * 4);
    int2*  t2sp   = (int2*)take((size_t)N_NODES * T2CAP * 8);   // 64 MB sparse T2

    hipMemsetAsync(deg, 0, (size_t)N_NODES * 4, stream);
    k_adj<<<N_NODES / 4, 256, 0, stream>>>(adj, deg, rdeg, rcolF);
    k_scan<<<1, 1024, 0, stream>>>(deg, dinv, colptr, colcur);
    k_vals<<<N_NODES / 4, 256, 0, stream>>>(dinv, rdeg, rcolF, rlvalF,
                                            colcur, col_i, val);
    k_sw<<<2, 256, 0, stream>>>(W, sW);
    k_t2<<<N_NODES, TB, 0, stream>>>(rdeg, rcolF, rlvalF, t2sp, t2cnt, sA);
    k_t3<<<N_NODES, TB, 0, stream>>>(rdeg, rcolF, rlvalF, t2sp, t2cnt, sA);
    k_cm<<<dim3(N_NODES / 32, KCH), 256, 0, stream>>>(r, sA, sW, W, M);
    k_h1<<<N_NODES / 2, 256, 0, stream>>>(colptr, col_i, val, M, B2);
    k_h2<<<N_NODES / 2, 256, 0, stream>>>(colptr, col_i, val, M, B2, B3);
    k_h3<<<N_NODES / 2, 256, 0, stream>>>(colptr, col_i, val, M, B3, out);
}

// Round 12
// 373.216 us; speedup vs baseline: 1.3045x; 1.1252x over previous
//
#include <hip/hip_runtime.h>
#include <cstdint>
#include <cstddef>

#define N_NODES 4096
#define FEAT 128
#define KCH 4
#define NNZ_CAP (1 << 18)   // col-CSR cap; expected nnz ~65.5K
#define TB 512              // threads for per-row T-kernels
#define T2CAP 2048          // sparse T2 row stride (expected ~273 nnz/row)
#define RSTRIDE 96          // fixed row-list stride (max out-degree ~40 expected)

// OpenBLAS sgemm K-panel boundaries for K=4096, GEMM_Q=384 (level3.c balancing):
// 0,384,768,1152,1536,1920,2304,2688,3072,3456,3776,4096
__device__ __forceinline__ int panel_of(int p) {
    return p < 3456 ? (p / 384) : (p < 3776 ? 9 : 10);
}

// ---- Single adjacency pass: per-row ascending column lists (fixed stride) + out-degree
//      + in-degree column counts (int atomics). One 64 MB read total.
__global__ __launch_bounds__(256) void k_adj(const float* __restrict__ adj,
                                             int* __restrict__ deg,
                                             int* __restrict__ rdeg,
                                             int* __restrict__ rcolF) {
    int row = (blockIdx.x * 256 + threadIdx.x) >> 6;   // wave per row
    int lane = threadIdx.x & 63;
    const float* rowp = adj + (size_t)row * N_NODES;
    int base = 0;
    for (int it = 0; it < 64; ++it) {
        int x = it * 64 + lane;
        bool nz = rowp[x] != 0.0f;
        unsigned long long m = __ballot(nz);
        if (nz) {
            int idx = base + __popcll(m & ((1ull << lane) - 1ull));
            if (idx < RSTRIDE) rcolF[row * RSTRIDE + idx] = x;
            atomicAdd(&deg[x], 1);
        }
        base += __popcll(m);
    }
    if (lane == 0) rdeg[row] = (base > RSTRIDE) ? RSTRIDE : base;
}

// ---- Scan: dinv = correctly-rounded fp32 d^-0.5; colptr/colcur from deg
__global__ __launch_bounds__(1024) void k_scan(const int* __restrict__ deg,
                                               float* __restrict__ dinv,
                                               int* __restrict__ colptr,
                                               int* __restrict__ colcur) {
    __shared__ int part[1024];
    int t = threadIdx.x;
    int v[4]; int s = 0;
    for (int c = 0; c < 4; ++c) {
        int idx = t * 4 + c;
        int di = deg[idx];
        v[c] = di;
        s += di;
        float dc = fmaxf((float)di, 1.0f);
        dinv[idx] = (float)(1.0 / sqrt((double)dc));  // correctly-rounded fp32 x^-0.5
    }
    part[t] = s;
    __syncthreads();
    for (int off = 1; off < 1024; off <<= 1) {
        int add = (t >= off) ? part[t - off] : 0;
        __syncthreads();
        part[t] += add;
        __syncthreads();
    }
    int base = (t == 0) ? 0 : part[t - 1];
    for (int c = 0; c < 4; ++c) {
        int idx = t * 4 + c;
        colptr[idx] = base; colcur[idx] = base;
        base += v[c];
    }
    if (t == 1023) colptr[N_NODES] = base;
}

// ---- Values pass (tiny): rlvalF = -fl(dinv_i*dinv_x); col-CSR (col_i, val) via cursors
__global__ __launch_bounds__(256) void k_vals(const float* __restrict__ dinv,
                                              const int* __restrict__ rdeg,
                                              const int* __restrict__ rcolF,
                                              float* __restrict__ rlvalF,
                                              int* __restrict__ colcur,
                                              int* __restrict__ col_i,
                                              float* __restrict__ val) {
    int row = (blockIdx.x * 256 + threadIdx.x) >> 6;
    int lane = threadIdx.x & 63;
    int n = rdeg[row];
    float di = dinv[row];
    for (int e = lane; e < n; e += 64) {
        int x = rcolF[row * RSTRIDE + e];
        float dv = di * dinv[x];
        rlvalF[row * RSTRIDE + e] = -dv;
        int ec = atomicAdd(&colcur[x], 1);
        if (ec < NNZ_CAP) { col_i[ec] = row; val[ec] = dv; }
    }
}

// ---- sW[k][j] = fp32 sequential sum over y (numpy strided-axis reduce order)
__global__ void k_sw(const float* __restrict__ W, float* __restrict__ sW) {
    int tid = blockIdx.x * blockDim.x + threadIdx.x;  // 0..511
    int k = tid >> 7, j = tid & 127;
    float s = 0.f;
    for (int y = 0; y < FEAT; ++y)
        s += fabsf(W[(size_t)j * (KCH * FEAT) + k * FEAT + y]);
    sW[k * FEAT + j] = s;
}

// ---- numpy pairwise_sum over 4096 contiguous fp32 (bitwise replication)
__device__ __forceinline__ float np_pairwise_4096(const float* __restrict__ row,
                                                  float* r256, float* leaf,
                                                  float* bc, int t) {
    if (t < 256) {
        int L = t >> 3, j = t & 7;
        const float* p = row + L * 128 + j;
        float a = p[0];
        #pragma unroll
        for (int q = 1; q < 16; ++q) a += p[8 * q];
        r256[t] = a;
    }
    __syncthreads();
    if (t < 32) {
        const float* rr = r256 + t * 8;
        leaf[t] = ((rr[0] + rr[1]) + (rr[2] + rr[3])) + ((rr[4] + rr[5]) + (rr[6] + rr[7]));
    }
    __syncthreads();
    if (t == 0) {
        float v[32];
        #pragma unroll
        for (int q = 0; q < 32; ++q) v[q] = leaf[q];
        #pragma unroll
        for (int w = 16; w >= 1; w >>= 1)
            #pragma unroll
            for (int q = 0; q < 16; ++q)
                if (q < w) v[q] = v[2 * q] + v[2 * q + 1];
        bc[0] = v[0];
    }
    __syncthreads();
    float res = bc[0];
    __syncthreads();
    return res;
}

// ---- k_t2 (bit-exact denom arithmetic, register-accumulator + float4 LDS layout):
//      s1 = pairwise(L-row); G = (L@L)_row with OpenBLAS kc-panels: q-ascending fmaf
//      scatter into gp (barrier per q), panel fold tot[u] += gp[x] in REGISTERS (one
//      rounding per panel per x, same order), gp zeroed by the fold. T2 = fl(2G - I)
//      written densely into gp; s2 = pairwise(gp); sparse emission.
__global__ __launch_bounds__(TB) void k_t2(const int* __restrict__ rdeg,
                                           const int* __restrict__ rcolF,
                                           const float* __restrict__ rlvalF,
                                           int2* __restrict__ t2sp,
                                           int* __restrict__ t2cnt,
                                           float* __restrict__ sA) {
    __shared__ float gp[N_NODES];     // panel partial; later T2 dense row
    __shared__ int   scol[2048];
    __shared__ float sval[2048];
    __shared__ int   pcol[64];
    __shared__ float pLip[64];
    __shared__ int   pbeg[64], plen[64], poff[65];
    __shared__ int   ssplit;
    __shared__ float r256[256], leaf[32], bc[1];
    __shared__ int   wtot[8], wbase[8];
    int t = threadIdx.x;
    int i = blockIdx.x;
    int rp = i * RSTRIDE;
    int ol = rdeg[i];                 // out-degree
    int cnt = ol + 1;                 // + diagonal
    if (cnt > 64) cnt = 64;
    if (t == 0) ssplit = 0;
    __syncthreads();
    if (t < ol && rcolF[rp + t] < i) atomicAdd(&ssplit, 1);
    __syncthreads();
    int split = ssplit;
    if (t < cnt) {
        int col; float lip;
        if (t < split)       { col = rcolF[rp + t];     lip = rlvalF[rp + t]; }
        else if (t == split) { col = i;                 lip = 1.0f; }
        else                 { col = rcolF[rp + t - 1]; lip = rlvalF[rp + t - 1]; }
        pcol[t] = col; pLip[t] = lip;
        pbeg[t] = col * RSTRIDE;
        plen[t] = rdeg[col] + 1;      // + synthetic diagonal
    }
    // float4 zero-init of gp
    float4* gp4 = (float4*)gp;
    const float4 z4 = make_float4(0.f, 0.f, 0.f, 0.f);
    #pragma unroll
    for (int u = 0; u < 2; ++u) gp4[t + u * TB] = z4;
    __syncthreads();
    if (t == 0) {
        int o = 0;
        for (int q = 0; q < cnt; ++q) { poff[q] = o; o += plen[q]; }
        poff[cnt] = o;
    }
    __syncthreads();
    int E = poff[cnt]; if (E > 2048) E = 2048;
    for (int idx = t; idx < E; idx += TB) {
        int lo = 0, hi = cnt - 1;
        while (lo < hi) { int mid = (lo + hi + 1) >> 1; if (poff[mid] <= idx) lo = mid; else hi = mid - 1; }
        int e = idx - poff[lo];
        if (e == plen[lo] - 1) { scol[idx] = pcol[lo]; sval[idx] = 1.0f; }
        else                   { scol[idx] = rcolF[pbeg[lo] + e]; sval[idx] = rlvalF[pbeg[lo] + e]; }
    }
    __syncthreads();
    // ---- s1: build dense L-row(i) in gp (zeroed), pairwise, sparse-clear
    int q0 = split;  // own-row segment (entries + synthetic diag) IS the L-row
    for (int e = t; e < plen[q0]; e += TB) { int idx = poff[q0] + e; gp[scol[idx]] = sval[idx]; }
    __syncthreads();
    float s1 = np_pairwise_4096(gp, r256, leaf, bc, t);
    for (int e = t; e < plen[q0]; e += TB) gp[scol[poff[q0] + e]] = 0.0f;
    __syncthreads();
    // ---- G = (L@L) row i: q-ascending fmaf scatter (barrier per q), register panel fold
    float tot[8];
    #pragma unroll
    for (int u = 0; u < 8; ++u) tot[u] = 0.0f;
    int q = 0;
    while (q < cnt) {
        int pid = panel_of(pcol[q]);
        while (q < cnt && panel_of(pcol[q]) == pid) {
            float lv = pLip[q];
            int o = poff[q], Lq = plen[q];
            for (int e = t; e < Lq; e += TB) {
                int idx = o + e; int x = scol[idx];
                gp[x] = fmaf(lv, sval[idx], gp[x]);
            }
            __syncthreads();
            ++q;
        }
        // panel-boundary rounding: tot[u] += gp[x] (regs), gp reset; float4 width
        #pragma unroll
        for (int u2 = 0; u2 < 2; ++u2) {
            int idx = t + u2 * TB;
            float4 b = gp4[idx];
            tot[4 * u2 + 0] = tot[4 * u2 + 0] + b.x;
            tot[4 * u2 + 1] = tot[4 * u2 + 1] + b.y;
            tot[4 * u2 + 2] = tot[4 * u2 + 2] + b.z;
            tot[4 * u2 + 3] = tot[4 * u2 + 3] + b.w;
            gp4[idx] = z4;
        }
        __syncthreads();
    }
    // T2 entries fl(2G - I), dense store from registers (x = 4t + 2048*u2 + c)
    #pragma unroll
    for (int u2 = 0; u2 < 2; ++u2) {
        int xb = 4 * t + 2048 * u2;
        float4 v;
        v.x = 2.0f * tot[4 * u2 + 0] - (xb + 0 == i ? 1.0f : 0.0f);
        v.y = 2.0f * tot[4 * u2 + 1] - (xb + 1 == i ? 1.0f : 0.0f);
        v.z = 2.0f * tot[4 * u2 + 2] - (xb + 2 == i ? 1.0f : 0.0f);
        v.w = 2.0f * tot[4 * u2 + 3] - (xb + 3 == i ? 1.0f : 0.0f);
        gp4[t + u2 * TB] = v;
    }
    __syncthreads();
    float s2 = np_pairwise_4096(gp, r256, leaf, bc, t);
    // ---- sparse emission (ascending col): thread t owns x in [8t, 8t+8), float4 reads
    float4 ea = gp4[2 * t], eb = gp4[2 * t + 1];
    float ev[8] = {ea.x, ea.y, ea.z, ea.w, eb.x, eb.y, eb.z, eb.w};
    int cl = 0;
    #pragma unroll
    for (int u = 0; u < 8; ++u) cl += (ev[u] != 0.0f);
    int lane = t & 63, wv = t >> 6;
    int sc = cl;
    for (int off = 1; off < 64; off <<= 1) {
        int n = __shfl_up(sc, off);
        if (lane >= off) sc += n;
    }
    if (lane == 63) wtot[wv] = sc;
    __syncthreads();
    if (t == 0) {
        int b = 0;
        for (int wq = 0; wq < 8; ++wq) { wbase[wq] = b; b += wtot[wq]; }
        t2cnt[i] = (b > T2CAP) ? T2CAP : b;
    }
    __syncthreads();
    int pos = wbase[wv] + sc - cl;
    int2* dst = t2sp + (size_t)i * T2CAP;
    #pragma unroll
    for (int u = 0; u < 8; ++u) {
        if (ev[u] != 0.0f) {
            if (pos < T2CAP) dst[pos] = make_int2(t * 8 + u, __float_as_int(ev[u]));
            ++pos;
        }
    }
    if (t == 0) {
        sA[0 * N_NODES + i] = 1.0f;
        sA[1 * N_NODES + i] = s1;
        sA[2 * N_NODES + i] = s2;
    }
}

// ---- k_t3 (bit-exact): sparse T2 scatter per q (barrier), float4 register panel fold.
//      T3 = fl(2H - T1); s3 = pairwise. T3 never stored.
__global__ __launch_bounds__(TB) void k_t3(const int* __restrict__ rdeg,
                                           const int* __restrict__ rcolF,
                                           const float* __restrict__ rlvalF,
                                           const int2* __restrict__ t2sp,
                                           const int* __restrict__ t2cnt,
                                           float* __restrict__ sA) {
    __shared__ float gp[N_NODES];     // panel partial, then final T3 row
    __shared__ int   pcol[64];
    __shared__ float pLip[64];
    __shared__ int   ssplit;
    __shared__ float r256[256], leaf[32], bc[1];
    int t = threadIdx.x;
    int i = blockIdx.x;
    int rp = i * RSTRIDE;
    int ol = rdeg[i];
    int cnt = ol + 1;
    if (cnt > 64) cnt = 64;
    if (t == 0) ssplit = 0;
    __syncthreads();
    if (t < ol && rcolF[rp + t] < i) atomicAdd(&ssplit, 1);
    __syncthreads();
    int split = ssplit;
    if (t < cnt) {
        if (t < split)       { pcol[t] = rcolF[rp + t];     pLip[t] = rlvalF[rp + t]; }
        else if (t == split) { pcol[t] = i;                  pLip[t] = 1.0f; }
        else                 { pcol[t] = rcolF[rp + t - 1];  pLip[t] = rlvalF[rp + t - 1]; }
    }
    float4* gp4 = (float4*)gp;
    const float4 z4 = make_float4(0.f, 0.f, 0.f, 0.f);
    #pragma unroll
    for (int u2 = 0; u2 < 2; ++u2) gp4[t + u2 * TB] = z4;
    __syncthreads();
    float tot[8];
    #pragma unroll
    for (int u = 0; u < 8; ++u) tot[u] = 0.0f;
    int q = 0;
    while (q < cnt) {
        int pid = panel_of(pcol[q]);
        while (q < cnt && panel_of(pcol[q]) == pid) {
            float lv = pLip[q];
            int p = pcol[q];
            int nn = t2cnt[p];
            const int2* sp = t2sp + (size_t)p * T2CAP;
            for (int e = t; e < nn; e += TB) {
                int2 en = sp[e];
                gp[en.x] = fmaf(lv, __int_as_float(en.y), gp[en.x]);
            }
            __syncthreads();
            ++q;
        }
        // panel-boundary rounding: fold partial into register totals, reset (float4)
        #pragma unroll
        for (int u2 = 0; u2 < 2; ++u2) {
            int idx = t + u2 * TB;
            float4 b = gp4[idx];
            tot[4 * u2 + 0] = tot[4 * u2 + 0] + b.x;
            tot[4 * u2 + 1] = tot[4 * u2 + 1] + b.y;
            tot[4 * u2 + 2] = tot[4 * u2 + 2] + b.z;
            tot[4 * u2 + 3] = tot[4 * u2 + 3] + b.w;
            gp4[idx] = z4;
        }
        __syncthreads();
    }
    #pragma unroll
    for (int u2 = 0; u2 < 2; ++u2) {
        float4 v;
        v.x = 2.0f * tot[4 * u2 + 0];
        v.y = 2.0f * tot[4 * u2 + 1];
        v.z = 2.0f * tot[4 * u2 + 2];
        v.w = 2.0f * tot[4 * u2 + 3];
        gp4[t + u2 * TB] = v;       // exact x2
    }
    __syncthreads();
    for (int e = t; e < ol; e += TB) { int x = rcolF[rp + e]; gp[x] = gp[x] - rlvalF[rp + e]; }
    if (t == 0) gp[i] = gp[i] - 1.0f;
    __syncthreads();
    float s3 = np_pairwise_4096(gp, r256, leaf, bc, t);
    if (t == 0) sA[3 * N_NODES + i] = s3;
}

// ---- Fused c + M: c[i,j] = r[i,j]/denom (exact k_c arithmetic: non-contracted,
//      ascending-k mul then add); M_k[i,y] = sum_j c[i,j]*|W[j,k*128+y]|
__global__ __launch_bounds__(256) void k_cm(const float* __restrict__ r,
                                            const float* __restrict__ sA,
                                            const float* __restrict__ sW,
                                            const float* __restrict__ W,
                                            float* __restrict__ M) {
#pragma clang fp contract(off)
    __shared__ float cl[32][FEAT];
    int k = blockIdx.y;
    int ib = blockIdx.x * 32;
    int tx = threadIdx.x;
    int y = tx & 127, half = tx >> 7;
    for (int m = tx; m < 32 * FEAT; m += 256) {
        int i = ib + (m >> 7), j = m & 127;
        float denom = 0.0f;
        #pragma unroll
        for (int k2 = 0; k2 < KCH; ++k2) {
            float p = sA[k2 * N_NODES + i] * sW[k2 * FEAT + j];
            denom = denom + p;
        }
        cl[m >> 7][m & 127] = r[(size_t)i * FEAT + j] / denom;
    }
    __syncthreads();
    float acc[16];
    #pragma unroll
    for (int u = 0; u < 16; ++u) acc[u] = 0.0f;
    for (int j = 0; j < FEAT; ++j) {
        float a = fabsf(W[(size_t)j * (KCH * FEAT) + k * FEAT + y]);
        #pragma unroll
        for (int u = 0; u < 16; ++u) acc[u] += a * cl[half * 16 + u][j];
    }
    #pragma unroll
    for (int u = 0; u < 16; ++u)
        M[(size_t)k * N_NODES * FEAT + (size_t)(ib + half * 16 + u) * FEAT + y] = acc[u];
}

// ---- Horner output chain: out = M0 - M2 + Lap(M1 - 3M3 + Lap(2M2 + Lap(4M3))),
//      Lap(A) = A - D^T A. Three gather applications total.
// h1: B2 = 2M2 + 4*(M3 - D'M3)
__global__ void k_h1(const int* __restrict__ colptr, const int* __restrict__ col_i,
                     const float* __restrict__ val, const float* __restrict__ M,
                     float* __restrict__ B2) {
    int x = blockIdx.x * 2 + (threadIdx.x >> 7);
    int y = threadIdx.x & 127;
    const float* M2 = M + (size_t)2 * N_NODES * FEAT;
    const float* M3 = M + (size_t)3 * N_NODES * FEAT;
    int e0 = colptr[x], e1 = colptr[x + 1];
    if (e1 > NNZ_CAP) e1 = NNZ_CAP;
    float g = 0.0f;
    for (int e = e0; e < e1; ++e)
        g += val[e] * M3[(size_t)col_i[e] * FEAT + y];
    size_t o = (size_t)x * FEAT + y;
    B2[o] = 2.0f * M2[o] + 4.0f * (M3[o] - g);
}

// h2: B3 = (M1 - 3M3) + (B2 - D'B2)
__global__ void k_h2(const int* __restrict__ colptr, const int* __restrict__ col_i,
                     const float* __restrict__ val, const float* __restrict__ M,
                     const float* __restrict__ B2, float* __restrict__ B3) {
    int x = blockIdx.x * 2 + (threadIdx.x >> 7);
    int y = threadIdx.x & 127;
    const float* M1 = M + (size_t)N_NODES * FEAT;
    const float* M3 = M + (size_t)3 * N_NODES * FEAT;
    int e0 = colptr[x], e1 = colptr[x + 1];
    if (e1 > NNZ_CAP) e1 = NNZ_CAP;
    float g = 0.0f;
    for (int e = e0; e < e1; ++e)
        g += val[e] * B2[(size_t)col_i[e] * FEAT + y];
    size_t o = (size_t)x * FEAT + y;
    B3[o] = (M1[o] - 3.0f * M3[o]) + (B2[o] - g);
}

// h3: out = (M0 - M2) + (B3 - D'B3)
__global__ void k_h3(const int* __restrict__ colptr, const int* __restrict__ col_i,
                     const float* __restrict__ val, const float* __restrict__ M,
                     const float* __restrict__ B3, float* __restrict__ out) {
    int x = blockIdx.x * 2 + (threadIdx.x >> 7);
    int y = threadIdx.x & 127;
    const float* M0 = M;
    const float* M2 = M + (size_t)2 * N_NODES * FEAT;
    int e0 = colptr[x], e1 = colptr[x + 1];
    if (e1 > NNZ_CAP) e1 = NNZ_CAP;
    float g = 0.0f;
    for (int e = e0; e < e1; ++e)
        g += val[e] * B3[(size_t)col_i[e] * FEAT + y];
    size_t o = (size_t)x * FEAT + y;
    out[o] = (M0[o] - M2[o]) + (B3[o] - g);
}

extern "C" void kernel_launch(void* const* d_in, const int* in_sizes, int n_in,
                              void* d_out, int out_size, void* d_ws, size_t ws_size,
                              hipStream_t stream) {
    const float* r   = (const float*)d_in[1];
    const float* adj = (const float*)d_in[2];
    const float* W   = (const float*)d_in[3];
    float* out = (float*)d_out;

    char* w = (char*)d_ws;
    auto take = [&](size_t bytes) {
        char* p = w;
        w += (bytes + 255) & ~(size_t)255;
        return p;
    };
    int*   deg    = (int*)take((size_t)N_NODES * 4);
    int*   rdeg   = (int*)take((size_t)N_NODES * 4);
    float* dinv   = (float*)take((size_t)N_NODES * 4);
    int*   colcur = (int*)take((size_t)N_NODES * 4);
    int*   colptr = (int*)take((size_t)(N_NODES + 1) * 4);
    int*   col_i  = (int*)take((size_t)NNZ_CAP * 4);
    float* val    = (float*)take((size_t)NNZ_CAP * 4);
    int*   rcolF  = (int*)take((size_t)N_NODES * RSTRIDE * 4);
    float* rlvalF = (float*)take((size_t)N_NODES * RSTRIDE * 4);
    float* sW     = (float*)take((size_t)KCH * FEAT * 4);
    float* sA     = (float*)take((size_t)KCH * N_NODES * 4);
    float* M      = (float*)take((size_t)KCH * N_NODES * FEAT * 4);
    float* B2     = (float*)take((size_t)N_NODES * FEAT * 4);
    float* B3     = (float*)take((size_t)N_NODES * FEAT * 4);
    int*   t2cnt  = (int*)take((size_t)N_NODES * 4);
    int2*  t2sp   = (int2*)take((size_t)N_NODES * T2CAP * 8);   // 64 MB sparse T2

    hipMemsetAsync(deg, 0, (size_t)N_NODES * 4, stream);
    k_adj<<<N_NODES / 4, 256, 0, stream>>>(adj, deg, rdeg, rcolF);
    k_scan<<<1, 1024, 0, stream>>>(deg, dinv, colptr, colcur);
    k_vals<<<N_NODES / 4, 256, 0, stream>>>(dinv, rdeg, rcolF, rlvalF,
                                            colcur, col_i, val);
    k_sw<<<2, 256, 0, stream>>>(W, sW);
    k_t2<<<N_NODES, TB, 0, stream>>>(rdeg, rcolF, rlvalF, t2sp, t2cnt, sA);
    k_t3<<<N_NODES, TB, 0, stream>>>(rdeg, rcolF, rlvalF, t2sp, t2cnt, sA);
    k_cm<<<dim3(N_NODES / 32, KCH), 256, 0, stream>>>(r, sA, sW, W, M);
    k_h1<<<N_NODES / 2, 256, 0, stream>>>(colptr, col_i, val, M, B2);
    k_h2<<<N_NODES / 2, 256, 0, stream>>>(colptr, col_i, val, M, B2, B3);
    k_h3<<<N_NODES / 2, 256, 0, stream>>>(colptr, col_i, val, M, B3, out);
}